// Round 1
// baseline (239.072 us; speedup 1.0000x reference)
//
#include <hip/hip_runtime.h>

typedef __bf16 bf16;
typedef _Float16 f16;
typedef __bf16 bf16x8 __attribute__((ext_vector_type(8)));
typedef _Float16 f16x4 __attribute__((ext_vector_type(4)));
typedef _Float16 f16x8 __attribute__((ext_vector_type(8)));
typedef float f32x4 __attribute__((ext_vector_type(4)));
typedef float f32x16 __attribute__((ext_vector_type(16)));

// async global->LDS, 16B/lane. LDS dest = wave-uniform base + lane*16.
__device__ __forceinline__ void async16(const void* g, void* l) {
  __builtin_amdgcn_global_load_lds(
      (const __attribute__((address_space(1))) unsigned int*)g,
      (__attribute__((address_space(3))) unsigned int*)l, 16, 0, 0);
}

// pack two f32 -> one dword of 2x bf16 (no builtin on gfx950)
__device__ __forceinline__ unsigned cvtpk(float a, float b) {
  unsigned r;
  asm("v_cvt_pk_bf16_f32 %0, %1, %2" : "=v"(r) : "v"(a), "v"(b));
  return r;
}

// exchange a[32..63] <-> b[0..31]
__device__ __forceinline__ void swap32(unsigned& a, unsigned& b) {
  asm("v_permlane32_swap_b32 %0, %1" : "+v"(a), "+v"(b));
}

// ---------------------------------------------------------------------------
// Cast fp32 -> fp16, vectorized x4
// ---------------------------------------------------------------------------
__global__ __launch_bounds__(256) void castx(const float* __restrict__ in,
                                             f16* __restrict__ out) {
  long i = ((long)blockIdx.x * 256 + threadIdx.x) * 4;
  f32x4 v = *(const f32x4*)(in + i);
  f16x4 o;
#pragma unroll
  for (int j = 0; j < 4; j++) o[j] = (f16)v[j];
  *(f16x4*)(out + i) = o;
}

// ---------------------------------------------------------------------------
// Transpose + cast: float in[R][C] -> f16 out[C][R].  block (32,8)
// ---------------------------------------------------------------------------
__global__ __launch_bounds__(256) void tcast(const float* __restrict__ in,
                                             f16* __restrict__ out, int R, int C) {
  __shared__ float tile[32][33];
  int tx = threadIdx.x, ty = threadIdx.y;
  int c = blockIdx.x * 32 + tx;
#pragma unroll
  for (int i = 0; i < 4; i++) {
    int r = blockIdx.y * 32 + ty + i * 8;
    tile[ty + i * 8][tx] = in[(long)r * C + c];
  }
  __syncthreads();
  int c2 = blockIdx.y * 32 + tx;
#pragma unroll
  for (int i = 0; i < 4; i++) {
    int r2 = blockIdx.x * 32 + ty + i * 8;
    out[(long)r2 * R + c2] = (f16)tile[tx][ty + i * 8];
  }
}

// ---------------------------------------------------------------------------
// V transpose: f16 src (qkv_f + 2048, row stride 3072) -> bf16 vt[b][h][d][n]
// ---------------------------------------------------------------------------
__global__ __launch_bounds__(256) void vtrans(const f16* __restrict__ src,
                                              bf16* __restrict__ vt) {
  __shared__ f16 tile[32][33];
  int tx = threadIdx.x, ty = threadIdx.y;
  int n0 = blockIdx.x * 32, d0 = blockIdx.y * 32, bh = blockIdx.z;
  int b = bh >> 4, h = bh & 15;
#pragma unroll
  for (int i = 0; i < 4; i++) {
    int n = n0 + ty + i * 8;
    tile[ty + i * 8][tx] = src[(long)(b * 2048 + n) * 3072 + h * 64 + d0 + tx];
  }
  __syncthreads();
#pragma unroll
  for (int i = 0; i < 4; i++) {
    int d = d0 + ty + i * 8;
    vt[((long)(bh * 64 + d)) * 2048 + n0 + tx] = (bf16)(float)tile[tx][ty + i * 8];
  }
}

// ---------------------------------------------------------------------------
// fp16 1-term GEMM: C[M,N] = A[M,K] @ B[N,K]^T. 128x128 tile, BK=32,
// fragment-order async staging, double-buffered (1 barrier/iter).
// 512 threads / 8 waves: wave = (wm 0..3, wn 0..1), 32x64 output each,
// acc[2][4]. Staging 2 async16/wave (A-tile w, B-tile w).
// MODE 0: fp32 partials via blockIdx.z split-K. MODE 1: f16 out.
// ---------------------------------------------------------------------------
template <int MODE>
__global__ __launch_bounds__(512) void gemm_f16(const f16* __restrict__ A_g,
                                                const f16* __restrict__ B_g,
                                                float* __restrict__ p0,
                                                float* __restrict__ p1,
                                                f16* __restrict__ outh,
                                                int M, int N, int K) {
  __shared__ __align__(16) f16 AL[2][4096], BL[2][4096];
  int t = threadIdx.x, lane = t & 63, w = t >> 6;
  int wm = w >> 1, wn = w & 1;
  int m0 = blockIdx.y * 128, n0 = blockIdx.x * 128;
  int fm = lane & 15, fq = lane >> 4;
  int kseg = K / gridDim.z;
  int kstart = blockIdx.z * kseg;
  int nk = kseg / 32;

  const f16* ap = A_g + (long)(m0 + w * 16 + fm) * K + kstart + fq * 8;
  const f16* bp = B_g + (long)(n0 + w * 16 + fm) * K + kstart + fq * 8;

  f32x4 acc[2][4];
#pragma unroll
  for (int i = 0; i < 2; i++)
#pragma unroll
    for (int j = 0; j < 4; j++) acc[i][j] = f32x4{0.f, 0.f, 0.f, 0.f};

  // prefetch tile 0 into buffer 0
  async16(ap, &AL[0][w * 512]);
  async16(bp, &BL[0][w * 512]);

  for (int it = 0; it < nk; it++) {
    int cur = it & 1;
    __syncthreads();  // drains prefetch for tile `it`; waves done with cur^1
    if (it < nk - 1) {
      int ko = (it + 1) * 32;
      async16(ap + ko, &AL[cur ^ 1][w * 512]);
      async16(bp + ko, &BL[cur ^ 1][w * 512]);
    }
    f16x8 a[2], bfr[4];
#pragma unroll
    for (int i = 0; i < 2; i++)
      a[i] = *(const f16x8*)&AL[cur][(wm * 2 + i) * 512 + lane * 8];
#pragma unroll
    for (int j = 0; j < 4; j++)
      bfr[j] = *(const f16x8*)&BL[cur][(wn * 4 + j) * 512 + lane * 8];
#pragma unroll
    for (int i = 0; i < 2; i++)
#pragma unroll
      for (int j = 0; j < 4; j++)
        acc[i][j] = __builtin_amdgcn_mfma_f32_16x16x32_f16(a[i], bfr[j], acc[i][j], 0, 0, 0);
  }

  float* dst = blockIdx.z ? p1 : p0;
#pragma unroll
  for (int i = 0; i < 2; i++)
#pragma unroll
    for (int j = 0; j < 4; j++) {
      int c = n0 + (wn * 4 + j) * 16 + fm;
#pragma unroll
      for (int e = 0; e < 4; e++) {
        int r = m0 + (wm * 2 + i) * 16 + fq * 4 + e;
        if (MODE == 0)
          dst[(long)r * N + c] = acc[i][j][e];
        else
          outh[(long)r * N + c] = (f16)acc[i][j][e];
      }
    }
}

// ---------------------------------------------------------------------------
// out = p0 + p1 + bias   (fp32, 4096x1024)
// ---------------------------------------------------------------------------
__global__ __launch_bounds__(256) void addbias(const float* __restrict__ p0,
                                               const float* __restrict__ p1,
                                               const float* __restrict__ bias,
                                               float* __restrict__ out) {
  long i = ((long)blockIdx.x * 256 + threadIdx.x) * 4;
  f32x4 a = *(const f32x4*)(p0 + i);
  f32x4 b = *(const f32x4*)(p1 + i);
  f32x4 c = *(const f32x4*)(bias + (i & 1023));
  *(f32x4*)(out + i) = a + b + c;
}

// ---------------------------------------------------------------------------
// RMSNorm (inner=1024) + RoPE, fp16 in (qkv_f, stride 3072), fp16 out.
// grid (4096, 2): y==0 -> q (scale 1/8), y==1 -> k.
// ---------------------------------------------------------------------------
__global__ __launch_bounds__(256) void normrope(const f16* __restrict__ src,
                                                const float* __restrict__ wqn,
                                                const float* __restrict__ wkn,
                                                f16* __restrict__ qf,
                                                f16* __restrict__ kf) {
  int row = blockIdx.x, which = blockIdx.y;
  const f16* sp = src + (long)row * 3072 + which * 1024;
  const float* w = which ? wkn : wqn;
  f16* oh = which ? kf : qf;
  float scale = which ? 1.0f : 0.125f;
  int t = threadIdx.x;
  int j0 = t * 4;

  f16x4 xh = *(const f16x4*)(sp + j0);
  float xv[4];
#pragma unroll
  for (int j = 0; j < 4; j++) xv[j] = (float)xh[j];
  float ss = xv[0] * xv[0] + xv[1] * xv[1] + xv[2] * xv[2] + xv[3] * xv[3];
#pragma unroll
  for (int off = 32; off > 0; off >>= 1) ss += __shfl_down(ss, off);
  __shared__ float red[4];
  if ((t & 63) == 0) red[t >> 6] = ss;
  __syncthreads();
  float total = red[0] + red[1] + red[2] + red[3];
  float nsc = rsqrtf(total * (1.0f / 1024.0f) + 1e-6f) * scale;

  int n = row & 2047;
  f16x4 o;
#pragma unroll
  for (int pp = 0; pp < 2; pp++) {
    int j = j0 + 2 * pp;
    int ii = (j & 63) >> 1;
    float theta = __expf((float)ii * (-9.210340371976184f / 32.0f));
    float ang = (float)n * theta;
    float sn, cs;
    __sincosf(ang, &sn, &cs);
    float a0 = xv[2 * pp] * nsc * w[j];
    float a1 = xv[2 * pp + 1] * nsc * w[j + 1];
    o[2 * pp] = (f16)(cs * a0 - sn * a1);
    o[2 * pp + 1] = (f16)(sn * a0 + cs * a1);
  }
  *(f16x4*)(oh + (long)row * 1024 + j0) = o;
}

// ---------------------------------------------------------------------------
// MFMA flash attention v2: 256 threads / 4 waves, 32 q-rows per wave
// (128/block) via 32x32x16 mfma, swapped operands:
//   S^T = mfma(K, Q)   -> lane holds P row (q = lane&31) in registers
//   O^T = mfma(V^T, P^T) -> P packed in-register (cvt_pk + permlane32_swap),
// so P never touches LDS. K/V tiles [64][64] double-buffered, chunk-XOR
// swizzled (chunk ^= row&7) via pre-swizzled async16 source + swizzled reads
// -> bank-balanced ds_read_b128. LDS read traffic per q-row is half of v1.
// Max-free softmax as before (s bounded; l fp32-safe). Output a fp16.
// ---------------------------------------------------------------------------
__global__ __launch_bounds__(256) void attn_mfma(const f16* __restrict__ qf,
                                                 const f16* __restrict__ kf,
                                                 const bf16* __restrict__ vt,
                                                 f16* __restrict__ af) {
  __shared__ __align__(16) f16 KhL[2][4096];   // [64 k][64 d], swizzled
  __shared__ __align__(16) bf16 VtL[2][4096];  // [64 d][64 n], swizzled

  int t = threadIdx.x;
  int lane = t & 63, w = t >> 6;  // wave w owns q-rows q0 + w*32 .. +32
  int lo5 = lane & 31, hi = lane >> 5;
  int b = blockIdx.z, h = blockIdx.y, q0 = blockIdx.x * 128;

  // Q B-frags (whole kernel): lane -> Q[q0+w*32+lo5][h*64 + ks*16 + hi*8 + j]
  const f16* qb = qf + ((long)(b * 2048 + q0 + w * 32 + lo5)) * 1024 + h * 64 + hi * 8;
  f16x8 qfr[4];
#pragma unroll
  for (int ks = 0; ks < 4; ks++) qfr[ks] = *(const f16x8*)(qb + ks * 16);

  // staging: 8 units of 8 rows x 128B per tile; wave w stages units 2w, 2w+1.
  // LDS[row][chunk c] = G[row][c ^ (row&7)]  (linear dest, swizzled source)
  int r8 = lane >> 3;
  int ch = (lane & 7) ^ r8;
  const char* kgb = (const char*)(kf + ((long)(b * 2048)) * 1024 + h * 64);
  const char* vgb = (const char*)(vt + ((long)((b * 16 + h) * 64)) * 2048);

  // swizzled read offsets (K and V share the 128B-row geometry)
  int koff[4];
#pragma unroll
  for (int ks = 0; ks < 4; ks++)
    koff[ks] = lo5 * 128 + ((ks * 32 + hi * 16) ^ ((lane & 7) << 4));

  f32x16 Ot[2];
#pragma unroll
  for (int i = 0; i < 16; i++) {
    Ot[0][i] = 0.f;
    Ot[1][i] = 0.f;
  }
  float l_ = 0.f;

#define STAGE(buf, kb)                                                        \
  {                                                                           \
    _Pragma("unroll") for (int uu = 0; uu < 2; uu++) {                        \
      int u = w * 2 + uu;                                                     \
      async16(kgb + ((long)((kb) * 64 + u * 8 + r8)) * 2048 + ch * 16,        \
              (char*)KhL[buf] + u * 1024);                                    \
      async16(vgb + ((long)(u * 8 + r8)) * 4096 + (long)(kb) * 128 + ch * 16, \
              (char*)VtL[buf] + u * 1024);                                    \
    }                                                                         \
  }

  STAGE(0, 0);

  for (int kb = 0; kb < 32; kb++) {
    int cur = kb & 1;
    __syncthreads();  // drains tile-kb prefetch; all waves off buffer cur^1
    if (kb < 31) STAGE(cur ^ 1, kb + 1);

    const char* kbase = (const char*)KhL[cur];
    const char* vbase = (const char*)VtL[cur];

    // S^T = K Q^T : two 32(k)x32(q) tiles
    f32x16 s0, s1;
#pragma unroll
    for (int i = 0; i < 16; i++) {
      s0[i] = 0.f;
      s1[i] = 0.f;
    }
#pragma unroll
    for (int ks = 0; ks < 4; ks++) {
      f16x8 k0 = *(const f16x8*)(kbase + koff[ks]);
      f16x8 k1 = *(const f16x8*)(kbase + 4096 + koff[ks]);
      s0 = __builtin_amdgcn_mfma_f32_32x32x16_f16(k0, qfr[ks], s0, 0, 0, 0);
      s1 = __builtin_amdgcn_mfma_f32_32x32x16_f16(k1, qfr[ks], s1, 0, 0, 0);
    }

    // p = exp(s); per-lane l sum (q = lo5 fixed); pack PV B-frags in-register.
    // lane holds P[q=lo5][k_local=(r&3)+8*(r>>2)+4*hi] per nt tile; frag ks
    // needs P[q=lo5][ks*16+hi*8+j]: cvt_pk pairs + permlane32_swap assembles.
    union PF {
      unsigned u[4];
      bf16x8 v;
    } pf[4];
#pragma unroll
    for (int nt = 0; nt < 2; nt++) {
      f32x16 s = nt ? s1 : s0;
      float pv[16];
#pragma unroll
      for (int r = 0; r < 16; r++) {
        pv[r] = __expf(s[r]);
        l_ += pv[r];
      }
#pragma unroll
      for (int g = 0; g < 2; g++) {
        unsigned c01 = cvtpk(pv[g * 8 + 0], pv[g * 8 + 1]);
        unsigned c23 = cvtpk(pv[g * 8 + 2], pv[g * 8 + 3]);
        unsigned c45 = cvtpk(pv[g * 8 + 4], pv[g * 8 + 5]);
        unsigned c67 = cvtpk(pv[g * 8 + 6], pv[g * 8 + 7]);
        swap32(c01, c45);  // -> frag dwords 0 and 2
        swap32(c23, c67);  // -> frag dwords 1 and 3
        pf[nt * 2 + g].u[0] = c01;
        pf[nt * 2 + g].u[1] = c23;
        pf[nt * 2 + g].u[2] = c45;
        pf[nt * 2 + g].u[3] = c67;
      }
    }

    // O^T += V^T P^T : two 32(d)x32(q) tiles
#pragma unroll
    for (int ks = 0; ks < 4; ks++) {
      bf16x8 v0 = *(const bf16x8*)(vbase + koff[ks]);
      bf16x8 v1 = *(const bf16x8*)(vbase + 4096 + koff[ks]);
      Ot[0] = __builtin_amdgcn_mfma_f32_32x32x16_bf16(v0, pf[ks].v, Ot[0], 0, 0, 0);
      Ot[1] = __builtin_amdgcn_mfma_f32_32x32x16_bf16(v1, pf[ks].v, Ot[1], 0, 0, 0);
    }
  }
#undef STAGE

  // lane + its hi-partner hold complementary k halves for q=lo5
  l_ += __shfl_xor(l_, 32);
  float inv = 1.0f / l_;

  // O^T[d][q=lo5]: d = dt*32 + (r&3) + 8*(r>>2) + 4*hi  -> f16x4 stores
  f16* op = af + ((long)(b * 2048 + q0 + w * 32 + lo5)) * 1024 + h * 64;
#pragma unroll
  for (int dt = 0; dt < 2; dt++)
#pragma unroll
    for (int g4 = 0; g4 < 4; g4++) {
      f16x4 o4;
#pragma unroll
      for (int e = 0; e < 4; e++) o4[e] = (f16)(Ot[dt][g4 * 4 + e] * inv);
      *(f16x4*)(op + dt * 32 + g4 * 8 + hi * 4) = o4;
    }
}

// ---------------------------------------------------------------------------
// Workspace (MB, peak 62; 76 proven safe), liveness:
//   [ 0, 8): xf        castx -> qkv-GEMM
//   [ 8,14): Wqkv_t    tcast x2 -> qkv-GEMM
//   [14,38): qkv_f     GEMM -> normrope / vtrans
//   [38,46): qf        normrope -> attn
//   [46,54): kf        normrope -> attn
//   [54,62): vt        vtrans -> attn
//   [ 0, 8): af        attn -> out-GEMM      (xf dead)
//   [ 8,10): Wo_t      tcast -> out-GEMM     (Wqkv_t dead)
//   [14,30): p0        out-GEMM -> addbias   (qkv_f dead)
//   [30,46): p1        out-GEMM -> addbias   (qkv_f tail + qf dead)
// ---------------------------------------------------------------------------
extern "C" void kernel_launch(void* const* d_in, const int* in_sizes, int n_in,
                              void* d_out, int out_size, void* d_ws, size_t ws_size,
                              hipStream_t stream) {
  const float* x = (const float*)d_in[0];
  const float* Wq = (const float*)d_in[1];
  const float* Wkv = (const float*)d_in[2];
  const float* nqw = (const float*)d_in[3];
  const float* nkw = (const float*)d_in[4];
  const float* Wo = (const float*)d_in[5];
  const float* bo = (const float*)d_in[6];
  float* out = (float*)d_out;

  char* ws = (char*)d_ws;
  const long MB = 1l << 20;
  f16* xf     = (f16*)(ws);
  f16* Wqkv_t = (f16*)(ws + 8 * MB);
  f16* qkv_f  = (f16*)(ws + 14 * MB);
  f16* qfb    = (f16*)(ws + 38 * MB);
  f16* kfb    = (f16*)(ws + 46 * MB);
  bf16* vtb   = (bf16*)(ws + 54 * MB);
  f16* afb    = (f16*)(ws);
  f16* Wo_t   = (f16*)(ws + 8 * MB);
  float* p0   = (float*)(ws + 14 * MB);
  float* p1   = (float*)(ws + 30 * MB);

  dim3 tb(32, 8);
  castx<<<4096, 256, 0, stream>>>(x, xf);
  tcast<<<dim3(32, 32), tb, 0, stream>>>(Wq, Wqkv_t, 1024, 1024);
  tcast<<<dim3(64, 32), tb, 0, stream>>>(Wkv, Wqkv_t + 1024l * 1024, 1024, 2048);

  gemm_f16<1><<<dim3(24, 32), 512, 0, stream>>>(xf, Wqkv_t, nullptr, nullptr,
                                                qkv_f, 4096, 3072, 1024);

  normrope<<<dim3(4096, 2), 256, 0, stream>>>(qkv_f, nqw, nkw, qfb, kfb);

  vtrans<<<dim3(64, 2, 32), tb, 0, stream>>>(qkv_f + 2048, vtb);

  attn_mfma<<<dim3(16, 16, 2), 256, 0, stream>>>(qfb, kfb, vtb, afb);

  tcast<<<dim3(32, 32), tb, 0, stream>>>(Wo, Wo_t, 1024, 1024);

  gemm_f16<0><<<dim3(8, 32, 2), 512, 0, stream>>>(afb, Wo_t, p0, p1, nullptr,
                                                  4096, 1024, 1024);

  addbias<<<4096, 256, 0, stream>>>(p0, p1, bo, out);
}